// Round 3
// baseline (674.164 us; speedup 1.0000x reference)
//
#include <hip/hip_runtime.h>
#include <hip/hip_bf16.h>

// Problem constants (ResNet-50 CBP head)
#define BATCH 8
#define CH    2048
#define LSP   784          // H*W = 28*28
#define KPAD  800          // pad K to 25*32 for MFMA k-steps
#define KSTEPS (KPAD/32)   // 25
#define DDIM  8192         // count-sketch dim (power of 2)
#define NCLS  200
#define NTILE 16           // 2048/128 tiles per dim
#define NPAIR 136          // NTILE*(NTILE+1)/2 symmetric tile pairs
#define NGRP  68           // 2 pairs chained per block

typedef __bf16 bf16x8 __attribute__((ext_vector_type(8)));
typedef float  f32x4  __attribute__((ext_vector_type(4)));

// fp32 -> bf16 round-to-nearest-even (bit pattern)
__device__ __forceinline__ unsigned short f2bf_rn(float f) {
    unsigned int u = __float_as_uint(f);
    unsigned int r = u + 0x7fffu + ((u >> 16) & 1u);
    return (unsigned short)(r >> 16);
}

// ---------------------------------------------------------------------------
// Kernel 1: split x (fp32, [B,C,784]) into hi/lo bf16 [B,C,KPAD], vec4.
// Also zero-inits y (first 65536 threads) so no separate memset dispatch.
// ---------------------------------------------------------------------------
__global__ __launch_bounds__(256) void split_kernel(
    const float* __restrict__ x,
    unsigned short* __restrict__ xhi,
    unsigned short* __restrict__ xlo,
    float* __restrict__ y)
{
    int idx = blockIdx.x * 256 + threadIdx.x;          // vec4 index
    if (idx < BATCH * DDIM) y[idx] = 0.0f;
    if (idx >= BATCH * CH * KPAD / 4) return;
    int v  = idx * 4;
    int bc = v / KPAD;
    int l  = v - bc * KPAD;                            // multiple of 4
    float4 xv = make_float4(0.f, 0.f, 0.f, 0.f);
    if (l < LSP)                                       // LSP%4==0: uniform per vec
        xv = *(const float4*)&x[(size_t)bc * LSP + l];
    ushort4 hv, lv;
    float f[4] = {xv.x, xv.y, xv.z, xv.w};
    unsigned short hu[4], lu[4];
#pragma unroll
    for (int i = 0; i < 4; ++i) {
        hu[i] = f2bf_rn(f[i]);
        float hf = __uint_as_float(((unsigned int)hu[i]) << 16);
        lu[i] = f2bf_rn(f[i] - hf);                    // residual, exact in fp32
    }
    hv.x = hu[0]; hv.y = hu[1]; hv.z = hu[2]; hv.w = hu[3];
    lv.x = lu[0]; lv.y = lu[1]; lv.z = lu[2]; lv.w = lu[3];
    *(ushort4*)&xhi[v] = hv;
    *(ushort4*)&xlo[v] = lv;
}

// ---------------------------------------------------------------------------
// Kernel 2: chained symmetric Gram tile pairs + interleaved scatter.
// grid = (68 pair-groups, 1, 8 batch), 256 threads (4 waves).
// Pair-0's LDS-bin scatter is interleaved into pair-1's k-loop (3 entries/step)
// so the ~3 cyc/lane-op ds_add stream overlaps MFMA + staging drain.
// ---------------------------------------------------------------------------
__device__ __forceinline__ void stage_tile(
    const unsigned short* __restrict__ src, size_t rowbase_elems,
    unsigned short* lds_tile, int wv, int lane, int k0)
{
#pragma unroll
    for (int half = 0; half < 2; ++half) {
        int ch  = wv * 2 + half;                       // 0..7 chunk of 8KB tile
        int row = ch * 16 + (lane >> 2);
        int kg  = (lane & 3) ^ ((lane >> 3) & 3);      // XOR swizzle (row>>1)&3
        const unsigned short* g = src + rowbase_elems
            + (size_t)row * KPAD + k0 + kg * 8;
        __builtin_amdgcn_global_load_lds(
            (__attribute__((address_space(1))) void*)g,
            (__attribute__((address_space(3))) void*)(lds_tile + ch * 512),
            16, 0, 0);
    }
}

// One scatter entry: Gram value acc[mi][ni][r] -> 1 (diag) or 2 (mirror) bins.
// mi/r/ni must be call-site constants (constant acc indexing -> no scratch).
__device__ __forceinline__ void scat_entry(
    float* bins, const f32x4 (&acc)[4][4], int mi, int r, int ni,
    int c1b,
    const int* __restrict__ h1, const float* __restrict__ s1,
    const int* __restrict__ h2, const float* __restrict__ s2,
    const int (&hh1)[4], const float (&ss1)[4],
    const int (&hh2)[4], const float (&ss2)[4],
    bool diag)
{
    const int c1 = c1b + mi * 16 + r;
    const float g = acc[mi][ni][r];
    const int   h1r = h1[c1];
    const float s1r = s1[c1];
    atomicAdd(&bins[(h1r + hh2[ni]) & (DDIM - 1)], s1r * ss2[ni] * g);
    if (!diag) {
        const int   h2r = h2[c1];
        const float s2r = s2[c1];
        atomicAdd(&bins[(hh1[ni] + h2r) & (DDIM - 1)], ss1[ni] * s2r * g);
    }
}

struct PairGeom { int tM, tN; bool diag; };

__device__ __forceinline__ PairGeom decode_pair(int p) {
    PairGeom g; g.tM = 0; g.tN = 0;
    int i = p;
#pragma unroll 1
    for (int t = 0; t < NTILE; ++t) {
        int cnt = NTILE - t;
        if (i < cnt) { g.tM = t; g.tN = t + i; break; }
        i -= cnt;
    }
    g.diag = (g.tM == g.tN);
    return g;
}

// Compute one 128x128 Gram tile pair into acc. If ilv, interleave the scatter
// of accPrev (pair-0) at 3 entries per k-step.
__device__ __forceinline__ void compute_pair(
    const unsigned short* __restrict__ xhi,
    const unsigned short* __restrict__ xlo,
    unsigned short* smA_hi, unsigned short* smA_lo,
    unsigned short* smB_hi, unsigned short* smB_lo,
    float* bins,
    int b, PairGeom pg, int wv, int lane,
    f32x4 (&acc)[4][4],
    bool ilv, const f32x4 (&accPrev)[4][4], int c1b0,
    const int* __restrict__ h1, const float* __restrict__ s1,
    const int* __restrict__ h2, const float* __restrict__ s2,
    const int (&hh1p)[4], const float (&ss1p)[4],
    const int (&hh2p)[4], const float (&ss2p)[4],
    bool diag0)
{
    const int wrow = (wv >> 1) * 64;
    const int wcol = (wv & 1) * 64;
    const size_t rowbaseA = ((size_t)b * CH + (size_t)pg.tM * 128) * KPAD;
    const size_t rowbaseB = ((size_t)b * CH + (size_t)pg.tN * 128) * KPAD;
    const unsigned short* fragBhi = pg.diag ? smA_hi : smB_hi;
    const unsigned short* fragBlo = pg.diag ? smA_lo : smB_lo;

    const f32x4 zv = {0.0f, 0.0f, 0.0f, 0.0f};
#pragma unroll
    for (int mi = 0; mi < 4; ++mi)
#pragma unroll
        for (int ni = 0; ni < 4; ++ni) acc[mi][ni] = zv;

    const int fxor = (((lane >> 4) ^ ((lane >> 1) & 3)) << 3);
    const int rsel = lane & 15;

#pragma unroll
    for (int ks = 0; ks < KSTEPS; ++ks) {
        const int k0 = ks * 32;
        stage_tile(xhi, rowbaseA, smA_hi, wv, lane, k0);
        stage_tile(xlo, rowbaseA, smA_lo, wv, lane, k0);
        if (!pg.diag) {
            stage_tile(xhi, rowbaseB, smB_hi, wv, lane, k0);
            stage_tile(xlo, rowbaseB, smB_lo, wv, lane, k0);
        }
        __syncthreads();

        bf16x8 ah[4], al[4], bh[4], bl[4];
#pragma unroll
        for (int i = 0; i < 4; ++i) {
            int offa = (wrow + i * 16 + rsel) * 32 + fxor;
            ah[i] = *(const bf16x8*)&smA_hi[offa];
            al[i] = *(const bf16x8*)&smA_lo[offa];
            int offb = (wcol + i * 16 + rsel) * 32 + fxor;
            bh[i] = *(const bf16x8*)&fragBhi[offb];
            bl[i] = *(const bf16x8*)&fragBlo[offb];
        }
#pragma unroll
        for (int mi = 0; mi < 4; ++mi)
#pragma unroll
            for (int ni = 0; ni < 4; ++ni) {
                acc[mi][ni] = __builtin_amdgcn_mfma_f32_16x16x32_bf16(ah[mi], bh[ni], acc[mi][ni], 0, 0, 0);
                acc[mi][ni] = __builtin_amdgcn_mfma_f32_16x16x32_bf16(ah[mi], bl[ni], acc[mi][ni], 0, 0, 0);
                acc[mi][ni] = __builtin_amdgcn_mfma_f32_16x16x32_bf16(al[mi], bh[ni], acc[mi][ni], 0, 0, 0);
            }

        // Interleaved scatter of previous pair's acc: 3 entries per k-step
        // (covers 64 entries by step 21). Entry index constants after unroll.
        if (ilv) {
#pragma unroll
            for (int e = 0; e < 3; ++e) {
                const int q = ks * 3 + e;
                if (q < 64)
                    scat_entry(bins, accPrev, (q >> 4) & 3, (q >> 2) & 3, q & 3,
                               c1b0, h1, s1, h2, s2,
                               hh1p, ss1p, hh2p, ss2p, diag0);
            }
        }
        __syncthreads();
    }
}

__global__ __launch_bounds__(256, 2) void gram_scatter_kernel(
    const unsigned short* __restrict__ xhi,
    const unsigned short* __restrict__ xlo,
    const int*   __restrict__ h1, const float* __restrict__ s1,
    const int*   __restrict__ h2, const float* __restrict__ s2,
    float* __restrict__ y)
{
    __shared__ __align__(16) unsigned short smA_hi[128 * 32];
    __shared__ __align__(16) unsigned short smA_lo[128 * 32];
    __shared__ __align__(16) unsigned short smB_hi[128 * 32];
    __shared__ __align__(16) unsigned short smB_lo[128 * 32];
    __shared__ float bins[DDIM];                       // 32 KB private histogram

    const int tid  = threadIdx.x;
    const int lane = tid & 63;
    const int wv   = tid >> 6;
    const int b    = blockIdx.z;

    const PairGeom pg0 = decode_pair(2 * blockIdx.x);
    const PairGeom pg1 = decode_pair(2 * blockIdx.x + 1);

    for (int i = tid; i < DDIM; i += 256) bins[i] = 0.0f;
    // (barriers inside pair-0's k-loop order this before any scatter)

    const int wrow = (wv >> 1) * 64;
    const int wcol = (wv & 1) * 64;

    f32x4 acc0[4][4], acc1[4][4];
    int   hh1d[4] = {0,0,0,0}; float ss1d[4] = {0,0,0,0};
    int   hh2d[4] = {0,0,0,0}; float ss2d[4] = {0,0,0,0};

    // ---- pair 0: compute only (no interleave) ----
    compute_pair(xhi, xlo, smA_hi, smA_lo, smB_hi, smB_lo, bins,
                 b, pg0, wv, lane, acc0,
                 false, acc0, 0, h1, s1, h2, s2,
                 hh1d, ss1d, hh2d, ss2d, true);

    // ---- preload pair-0 scatter meta ----
    const int c2b0 = pg0.tN * 128 + wcol + (lane & 15);
    const int c1b0 = pg0.tM * 128 + wrow + ((lane >> 4) << 2);
    int   hh1p[4], hh2p[4]; float ss1p[4], ss2p[4];
#pragma unroll
    for (int ni = 0; ni < 4; ++ni) {
        int c2 = c2b0 + ni * 16;
        hh1p[ni] = h1[c2]; ss1p[ni] = s1[c2];
        hh2p[ni] = h2[c2]; ss2p[ni] = s2[c2];
    }

    // ---- pair 1: compute + interleave pair-0 scatter ----
    compute_pair(xhi, xlo, smA_hi, smA_lo, smB_hi, smB_lo, bins,
                 b, pg1, wv, lane, acc1,
                 true, acc0, c1b0, h1, s1, h2, s2,
                 hh1p, ss1p, hh2p, ss2p, pg0.diag);

    // ---- scatter pair-1's acc (straight-line) ----
    const int c2b1 = pg1.tN * 128 + wcol + (lane & 15);
    const int c1b1 = pg1.tM * 128 + wrow + ((lane >> 4) << 2);
    int   hh1q[4], hh2q[4]; float ss1q[4], ss2q[4];
#pragma unroll
    for (int ni = 0; ni < 4; ++ni) {
        int c2 = c2b1 + ni * 16;
        hh1q[ni] = h1[c2]; ss1q[ni] = s1[c2];
        hh2q[ni] = h2[c2]; ss2q[ni] = s2[c2];
    }
#pragma unroll
    for (int mi = 0; mi < 4; ++mi)
#pragma unroll
        for (int r = 0; r < 4; ++r)
#pragma unroll
            for (int ni = 0; ni < 4; ++ni)
                scat_entry(bins, acc1, mi, r, ni, c1b1, h1, s1, h2, s2,
                           hh1q, ss1q, hh2q, ss2q, pg1.diag);

    __syncthreads();   // all scatters into bins complete
    float* yb = y + (size_t)b * DDIM;
    for (int i = tid; i < DDIM; i += 256) {
        float v = bins[i];
        if (v != 0.0f) atomicAdd(&yb[i], v);
    }
}

// ---------------------------------------------------------------------------
// Kernel 3 (merged head): feat = signed-sqrt + L2-normalize, then
// logit = feat @ W + b.  One block per batch; feat cached in LDS; W access
// coalesced (lane n reads W[d*200+n], consecutive across lanes).
// ---------------------------------------------------------------------------
__global__ __launch_bounds__(256) void head_kernel(
    const float* __restrict__ y, const float* __restrict__ W,
    const float* __restrict__ bc, float* __restrict__ out)
{
    const int b = blockIdx.x;
    const int tid = threadIdx.x;
    __shared__ float featLDS[DDIM];    // 32 KB
    __shared__ float red[256];

    float ss = 0.0f;
    for (int i = tid; i < DDIM; i += 256) ss += fabsf(y[(size_t)b * DDIM + i]);
    red[tid] = ss;
    __syncthreads();
    for (int s = 128; s > 0; s >>= 1) {
        if (tid < s) red[tid] += red[tid + s];
        __syncthreads();
    }
    const float inv = 1.0f / fmaxf(sqrtf(red[0]), 1e-12f);   // ||feat||=sqrt(sum|y|)
    for (int i = tid; i < DDIM; i += 256) {
        float v = y[(size_t)b * DDIM + i];
        float t = copysignf(sqrtf(fabsf(v)), v) * inv;
        featLDS[i] = t;
        out[BATCH * NCLS + (size_t)b * DDIM + i] = t;
    }
    __syncthreads();
    if (tid < NCLS) {
        float a0 = 0.f, a1 = 0.f, a2 = 0.f, a3 = 0.f;
        for (int d = 0; d < DDIM; d += 4) {
            a0 += featLDS[d]     * W[(size_t)d       * NCLS + tid];
            a1 += featLDS[d + 1] * W[(size_t)(d + 1) * NCLS + tid];
            a2 += featLDS[d + 2] * W[(size_t)(d + 2) * NCLS + tid];
            a3 += featLDS[d + 3] * W[(size_t)(d + 3) * NCLS + tid];
        }
        out[(size_t)b * NCLS + tid] = a0 + a1 + a2 + a3 + bc[tid];
    }
}

// ---------------------------------------------------------------------------
extern "C" void kernel_launch(void* const* d_in, const int* in_sizes, int n_in,
                              void* d_out, int out_size, void* d_ws, size_t ws_size,
                              hipStream_t stream)
{
    const float* x  = (const float*)d_in[0];
    const float* s1 = (const float*)d_in[1];
    const float* s2 = (const float*)d_in[2];
    const float* W  = (const float*)d_in[3];
    const float* bc = (const float*)d_in[4];
    const int*   h1 = (const int*)d_in[5];
    const int*   h2 = (const int*)d_in[6];
    float* out = (float*)d_out;

    // workspace layout: y (256KB) | xhi (25MB) | xlo (25MB)
    char* ws = (char*)d_ws;
    float* y = (float*)ws;
    const size_t ybytes = (size_t)BATCH * DDIM * sizeof(float);
    unsigned short* xhi = (unsigned short*)(ws + ybytes);
    unsigned short* xlo = (unsigned short*)(ws + ybytes + (size_t)BATCH * CH * KPAD * 2);

    split_kernel<<<(BATCH * CH * KPAD / 4 + 255) / 256, 256, 0, stream>>>(x, xhi, xlo, y);

    dim3 grid_g(NGRP, 1, BATCH);   // 2 chained pairs per block
    gram_scatter_kernel<<<grid_g, 256, 0, stream>>>(xhi, xlo, h1, s1, h2, s2, y);

    head_kernel<<<BATCH, 256, 0, stream>>>(y, W, bc, out);
}

// Round 4
// 431.623 us; speedup vs baseline: 1.5619x; 1.5619x over previous
//
#include <hip/hip_runtime.h>
#include <hip/hip_bf16.h>

// Problem constants (ResNet-50 CBP head)
#define BATCH 8
#define CH    2048
#define LSP   784          // H*W = 28*28
#define KPAD  800          // pad K to 25*32 for MFMA k-steps
#define KSTEPS (KPAD/32)   // 25
#define DDIM  8192         // count-sketch dim (power of 2)
#define NCLS  200
#define NTILE 16           // 2048/128 tiles per dim
#define NPAIR 136          // NTILE*(NTILE+1)/2 symmetric tile pairs

typedef __bf16 bf16x8 __attribute__((ext_vector_type(8)));
typedef float  f32x4  __attribute__((ext_vector_type(4)));

// fp32 -> bf16 round-to-nearest-even (bit pattern)
__device__ __forceinline__ unsigned short f2bf_rn(float f) {
    unsigned int u = __float_as_uint(f);
    unsigned int r = u + 0x7fffu + ((u >> 16) & 1u);
    return (unsigned short)(r >> 16);
}

// ---------------------------------------------------------------------------
// Kernel 1: split x (fp32, [B,C,784]) into hi/lo bf16 [B,C,KPAD], vec4.
// Also zero-inits y so no separate memset dispatch.
// ---------------------------------------------------------------------------
__global__ __launch_bounds__(256) void split_kernel(
    const float* __restrict__ x,
    unsigned short* __restrict__ xhi,
    unsigned short* __restrict__ xlo,
    float* __restrict__ y)
{
    int idx = blockIdx.x * 256 + threadIdx.x;          // vec4 index
    if (idx < BATCH * DDIM) y[idx] = 0.0f;
    if (idx >= BATCH * CH * KPAD / 4) return;
    int v  = idx * 4;
    int bc = v / KPAD;
    int l  = v - bc * KPAD;                            // multiple of 4
    float4 xv = make_float4(0.f, 0.f, 0.f, 0.f);
    if (l < LSP)                                       // LSP%4==0: uniform per vec
        xv = *(const float4*)&x[(size_t)bc * LSP + l];
    ushort4 hv, lv;
    float f[4] = {xv.x, xv.y, xv.z, xv.w};
    unsigned short hu[4], lu[4];
#pragma unroll
    for (int i = 0; i < 4; ++i) {
        hu[i] = f2bf_rn(f[i]);
        float hf = __uint_as_float(((unsigned int)hu[i]) << 16);
        lu[i] = f2bf_rn(f[i] - hf);                    // residual, exact in fp32
    }
    hv.x = hu[0]; hv.y = hu[1]; hv.z = hu[2]; hv.w = hu[3];
    lv.x = lu[0]; lv.y = lu[1]; lv.z = lu[2]; lv.w = lu[3];
    *(ushort4*)&xhi[v] = hv;
    *(ushort4*)&xlo[v] = lv;
}

// ---------------------------------------------------------------------------
// Kernel 2: symmetric Gram tile (bf16-split MFMA) + count-sketch scatter.
// grid = 1088 blocks 1-D:  batch = id & 7  (one batch per XCD under the
// id%8 round-robin XCD mapping -> per-XCD L2 working set = 6.55 MB, shared
// by ~64 co-resident same-batch blocks), pair = id >> 3 (row-major triangle
// so consecutive blocks share the A tile).
// LDS XOR-swizzle keeps fragment ds_read_b128 bank-conflict-free.
// ---------------------------------------------------------------------------
__device__ __forceinline__ void stage_tile(
    const unsigned short* __restrict__ src, size_t rowbase_elems,
    unsigned short* lds_tile, int wv, int lane, int k0)
{
#pragma unroll
    for (int half = 0; half < 2; ++half) {
        int ch  = wv * 2 + half;                       // 0..7 chunk of 8KB tile
        int row = ch * 16 + (lane >> 2);
        int kg  = (lane & 3) ^ ((lane >> 3) & 3);      // XOR swizzle (row>>1)&3
        const unsigned short* g = src + rowbase_elems
            + (size_t)row * KPAD + k0 + kg * 8;
        __builtin_amdgcn_global_load_lds(
            (__attribute__((address_space(1))) void*)g,
            (__attribute__((address_space(3))) void*)(lds_tile + ch * 512),
            16, 0, 0);
    }
}

__global__ __launch_bounds__(256, 2) void gram_scatter_kernel(
    const unsigned short* __restrict__ xhi,
    const unsigned short* __restrict__ xlo,
    const int*   __restrict__ h1, const float* __restrict__ s1,
    const int*   __restrict__ h2, const float* __restrict__ s2,
    float* __restrict__ y)
{
    __shared__ __align__(16) unsigned short smA_hi[128 * 32];
    __shared__ __align__(16) unsigned short smA_lo[128 * 32];
    __shared__ __align__(16) unsigned short smB_hi[128 * 32];
    __shared__ __align__(16) unsigned short smB_lo[128 * 32];
    __shared__ float bins[DDIM];                       // 32 KB private histogram

    const int tid  = threadIdx.x;
    const int lane = tid & 63;
    const int wv   = tid >> 6;
    const int b    = blockIdx.x & 7;       // batch in low bits -> one batch/XCD
    const int pidx = blockIdx.x >> 3;      // triangular pair index

    // Triangular decode: pidx in [0,136) -> (tM, tN), tM <= tN, row-major
    int tM = 0, tN = 0;
    {
        int i = pidx;
#pragma unroll 1
        for (int t = 0; t < NTILE; ++t) {
            int cnt = NTILE - t;
            if (i < cnt) { tM = t; tN = t + i; break; }
            i -= cnt;
        }
    }
    const bool diag = (tM == tN);

    for (int i = tid; i < DDIM; i += 256) bins[i] = 0.0f;
    // (first __syncthreads inside k-loop orders this before any scatter)

    const int wrow = (wv >> 1) * 64;    // wave's 64x64 subtile origin
    const int wcol = (wv & 1) * 64;

    const size_t rowbaseA = ((size_t)b * CH + (size_t)tM * 128) * KPAD;
    const size_t rowbaseB = ((size_t)b * CH + (size_t)tN * 128) * KPAD;

    const unsigned short* fragBhi = diag ? smA_hi : smB_hi;
    const unsigned short* fragBlo = diag ? smA_lo : smB_lo;

    f32x4 acc[4][4];
    const f32x4 zv = {0.0f, 0.0f, 0.0f, 0.0f};
#pragma unroll
    for (int mi = 0; mi < 4; ++mi)
#pragma unroll
        for (int ni = 0; ni < 4; ++ni) acc[mi][ni] = zv;

    // fragment LDS offset: (row)*32 + fxor; XOR term is a per-lane constant
    const int fxor = (((lane >> 4) ^ ((lane >> 1) & 3)) << 3);
    const int rsel = lane & 15;

    for (int ks = 0; ks < KSTEPS; ++ks) {
        const int k0 = ks * 32;
        stage_tile(xhi, rowbaseA, smA_hi, wv, lane, k0);
        stage_tile(xlo, rowbaseA, smA_lo, wv, lane, k0);
        if (!diag) {
            stage_tile(xhi, rowbaseB, smB_hi, wv, lane, k0);
            stage_tile(xlo, rowbaseB, smB_lo, wv, lane, k0);
        }
        __syncthreads();

        bf16x8 ah[4], al[4], bh[4], bl[4];
#pragma unroll
        for (int i = 0; i < 4; ++i) {
            int offa = (wrow + i * 16 + rsel) * 32 + fxor;
            ah[i] = *(const bf16x8*)&smA_hi[offa];
            al[i] = *(const bf16x8*)&smA_lo[offa];
            int offb = (wcol + i * 16 + rsel) * 32 + fxor;
            bh[i] = *(const bf16x8*)&fragBhi[offb];
            bl[i] = *(const bf16x8*)&fragBlo[offb];
        }
#pragma unroll
        for (int mi = 0; mi < 4; ++mi)
#pragma unroll
            for (int ni = 0; ni < 4; ++ni) {
                acc[mi][ni] = __builtin_amdgcn_mfma_f32_16x16x32_bf16(ah[mi], bh[ni], acc[mi][ni], 0, 0, 0);
                acc[mi][ni] = __builtin_amdgcn_mfma_f32_16x16x32_bf16(ah[mi], bl[ni], acc[mi][ni], 0, 0, 0);
                acc[mi][ni] = __builtin_amdgcn_mfma_f32_16x16x32_bf16(al[mi], bh[ni], acc[mi][ni], 0, 0, 0);
            }
        __syncthreads();
    }

    // Scatter the 128x128 Gram tile into the LDS histogram.
    // C/D layout (m89-verified): col = lane&15, row = (lane>>4)*4 + reg
    // Off-diagonal pair: each entry contributes twice (G symmetric).
    const int c2b = tN * 128 + wcol + (lane & 15);
    const int c1b = tM * 128 + wrow + ((lane >> 4) << 2);
    int   h1c[4], h2c[4]; float s1c[4], s2c[4];
#pragma unroll
    for (int ni = 0; ni < 4; ++ni) {
        int c2 = c2b + ni * 16;
        h1c[ni] = h1[c2]; s1c[ni] = s1[c2];
        h2c[ni] = h2[c2]; s2c[ni] = s2[c2];
    }
#pragma unroll
    for (int mi = 0; mi < 4; ++mi) {
#pragma unroll
        for (int r = 0; r < 4; ++r) {
            const int c1 = c1b + mi * 16 + r;
            const int h1r = h1[c1]; const float s1r = s1[c1];
            const int h2r = h2[c1]; const float s2r = s2[c1];
#pragma unroll
            for (int ni = 0; ni < 4; ++ni) {
                float g = acc[mi][ni][r];
                atomicAdd(&bins[(h1r + h2c[ni]) & (DDIM - 1)], s1r * s2c[ni] * g);
                if (!diag)
                    atomicAdd(&bins[(h1c[ni] + h2r) & (DDIM - 1)], s1c[ni] * s2r * g);
            }
        }
    }

    __syncthreads();   // all scatters into bins complete
    float* yb = y + (size_t)b * DDIM;
    for (int i = tid; i < DDIM; i += 256) {
        float v = bins[i];
        if (v != 0.0f) atomicAdd(&yb[i], v);
    }
}

// ---------------------------------------------------------------------------
// Kernel 3: feat = sign(y)*sqrt(|y|) / max(||.||2, 1e-12)   (one block per b)
// Also seeds logit[b,:] = b_cls (runs before logit_kernel in stream order).
// Note sum(feat_unnorm^2) == sum(|y|).
// ---------------------------------------------------------------------------
__global__ __launch_bounds__(256) void feat_kernel(
    const float* __restrict__ y, const float* __restrict__ bc,
    float* __restrict__ out)
{
    const int b = blockIdx.x;
    const int tid = threadIdx.x;
    __shared__ float red[256];
    float ss = 0.0f;
    for (int i = tid; i < DDIM; i += 256) ss += fabsf(y[(size_t)b * DDIM + i]);
    red[tid] = ss;
    __syncthreads();
    for (int s = 128; s > 0; s >>= 1) {
        if (tid < s) red[tid] += red[tid + s];
        __syncthreads();
    }
    const float inv = 1.0f / fmaxf(sqrtf(red[0]), 1e-12f);
    for (int i = tid; i < DDIM; i += 256) {
        float v = y[(size_t)b * DDIM + i];
        out[BATCH * NCLS + (size_t)b * DDIM + i] = copysignf(sqrtf(fabsf(v)), v) * inv;
    }
    if (tid < NCLS) out[(size_t)b * NCLS + tid] = bc[tid];
}

// ---------------------------------------------------------------------------
// Kernel 4: logit partials.  64 blocks, block j owns d in [128j,128j+128).
// Coalesced W reads (lane n -> W[d*200+n]); feat slice broadcast from LDS;
// one atomicAdd per (b, n) per block into the bias-seeded logits.
// ---------------------------------------------------------------------------
__global__ __launch_bounds__(256) void logit_kernel(
    const float* __restrict__ feat_base, const float* __restrict__ W,
    float* __restrict__ out)
{
    const int j = blockIdx.x;
    const int tid = threadIdx.x;
    __shared__ float fs[BATCH][128];                   // 4 KB
    for (int i = tid; i < BATCH * 128; i += 256) {
        int bb = i >> 7, dd = i & 127;
        fs[bb][dd] = feat_base[(size_t)bb * DDIM + j * 128 + dd];
    }
    __syncthreads();
    if (tid < NCLS) {
        float a[BATCH];
#pragma unroll
        for (int bb = 0; bb < BATCH; ++bb) a[bb] = 0.0f;
        for (int dd = 0; dd < 128; ++dd) {
            float w = W[(size_t)(j * 128 + dd) * NCLS + tid];
#pragma unroll
            for (int bb = 0; bb < BATCH; ++bb) a[bb] += fs[bb][dd] * w;
        }
#pragma unroll
        for (int bb = 0; bb < BATCH; ++bb)
            atomicAdd(&out[bb * NCLS + tid], a[bb]);
    }
}

// ---------------------------------------------------------------------------
extern "C" void kernel_launch(void* const* d_in, const int* in_sizes, int n_in,
                              void* d_out, int out_size, void* d_ws, size_t ws_size,
                              hipStream_t stream)
{
    const float* x  = (const float*)d_in[0];
    const float* s1 = (const float*)d_in[1];
    const float* s2 = (const float*)d_in[2];
    const float* W  = (const float*)d_in[3];
    const float* bc = (const float*)d_in[4];
    const int*   h1 = (const int*)d_in[5];
    const int*   h2 = (const int*)d_in[6];
    float* out = (float*)d_out;

    // workspace layout: y (256KB) | xhi (25MB) | xlo (25MB)
    char* ws = (char*)d_ws;
    float* y = (float*)ws;
    const size_t ybytes = (size_t)BATCH * DDIM * sizeof(float);
    unsigned short* xhi = (unsigned short*)(ws + ybytes);
    unsigned short* xlo = (unsigned short*)(ws + ybytes + (size_t)BATCH * CH * KPAD * 2);

    split_kernel<<<(BATCH * CH * KPAD / 4 + 255) / 256, 256, 0, stream>>>(x, xhi, xlo, y);

    gram_scatter_kernel<<<NPAIR * BATCH, 256, 0, stream>>>(xhi, xlo, h1, s1, h2, s2, y);

    feat_kernel<<<BATCH, 256, 0, stream>>>(y, bc, out);

    logit_kernel<<<64, 256, 0, stream>>>(out + BATCH * NCLS, W, out);
}

// Round 5
// 420.472 us; speedup vs baseline: 1.6034x; 1.0265x over previous
//
#include <hip/hip_runtime.h>
#include <hip/hip_bf16.h>

// Problem constants (ResNet-50 CBP head)
#define BATCH 8
#define CH    2048
#define LSP   784          // H*W = 28*28
#define KPAD  800          // pad K to 25*32 for MFMA k-steps
#define KSTEPS (KPAD/32)   // 25
#define DDIM  8192         // count-sketch dim (power of 2)
#define NCLS  200
#define NTILE 16           // 2048/128 tiles per dim
#define NPAIR 136          // NTILE*(NTILE+1)/2 symmetric tile pairs
#define NSLOT 17           // part slots per batch (136/17 = 8 blocks share a slot)

typedef __bf16 bf16x8 __attribute__((ext_vector_type(8)));
typedef float  f32x4  __attribute__((ext_vector_type(4)));

// fp32 -> bf16 round-to-nearest-even (bit pattern)
__device__ __forceinline__ unsigned short f2bf_rn(float f) {
    unsigned int u = __float_as_uint(f);
    unsigned int r = u + 0x7fffu + ((u >> 16) & 1u);
    return (unsigned short)(r >> 16);
}

// ---------------------------------------------------------------------------
// Kernel 1: split x into hi/lo bf16 [B,C,KPAD] (vec4).  Also zero-inits the
// part array + norm accumulators and seeds logits with the bias.
// ---------------------------------------------------------------------------
__global__ __launch_bounds__(256) void split_kernel(
    const float* __restrict__ x,
    unsigned short* __restrict__ xhi,
    unsigned short* __restrict__ xlo,
    float* __restrict__ part, float* __restrict__ norm,
    const float* __restrict__ bc, float* __restrict__ out)
{
    int idx = blockIdx.x * 256 + threadIdx.x;          // vec4 index
    if (idx < NSLOT * BATCH * DDIM) part[idx] = 0.0f;
    if (idx < BATCH) norm[idx] = 0.0f;
    if (idx < BATCH * NCLS) out[idx] = bc[idx % NCLS]; // bias-seed logits
    if (idx >= BATCH * CH * KPAD / 4) return;
    int v  = idx * 4;
    int bc_ = v / KPAD;
    int l  = v - bc_ * KPAD;                           // multiple of 4
    float4 xv = make_float4(0.f, 0.f, 0.f, 0.f);
    if (l < LSP)                                       // LSP%4==0: uniform per vec
        xv = *(const float4*)&x[(size_t)bc_ * LSP + l];
    ushort4 hv, lv;
    float f[4] = {xv.x, xv.y, xv.z, xv.w};
    unsigned short hu[4], lu[4];
#pragma unroll
    for (int i = 0; i < 4; ++i) {
        hu[i] = f2bf_rn(f[i]);
        float hf = __uint_as_float(((unsigned int)hu[i]) << 16);
        lu[i] = f2bf_rn(f[i] - hf);                    // residual, exact in fp32
    }
    hv.x = hu[0]; hv.y = hu[1]; hv.z = hu[2]; hv.w = hu[3];
    lv.x = lu[0]; lv.y = lu[1]; lv.z = lu[2]; lv.w = lu[3];
    *(ushort4*)&xhi[v] = hv;
    *(ushort4*)&xlo[v] = lv;
}

// ---------------------------------------------------------------------------
// Kernel 2: symmetric Gram tile (bf16-split MFMA) + count-sketch scatter.
// grid = 1088 blocks 1-D: batch = id & 7 (one batch per XCD -> 6.55 MB L2
// working set), pair = id >> 3 (row-major triangle).
// Scatter meta (h1,s1,h2,s2 per c1-row) staged in LDS -> no global gathers
// in the atomic loop.  Flush spread over 17 part slots with rotated order.
// ---------------------------------------------------------------------------
__device__ __forceinline__ void stage_tile(
    const unsigned short* __restrict__ src, size_t rowbase_elems,
    unsigned short* lds_tile, int wv, int lane, int k0)
{
#pragma unroll
    for (int half = 0; half < 2; ++half) {
        int ch  = wv * 2 + half;                       // 0..7 chunk of 8KB tile
        int row = ch * 16 + (lane >> 2);
        int kg  = (lane & 3) ^ ((lane >> 3) & 3);      // XOR swizzle (row>>1)&3
        const unsigned short* g = src + rowbase_elems
            + (size_t)row * KPAD + k0 + kg * 8;
        __builtin_amdgcn_global_load_lds(
            (__attribute__((address_space(1))) void*)g,
            (__attribute__((address_space(3))) void*)(lds_tile + ch * 512),
            16, 0, 0);
    }
}

__global__ __launch_bounds__(256, 2) void gram_scatter_kernel(
    const unsigned short* __restrict__ xhi,
    const unsigned short* __restrict__ xlo,
    const int*   __restrict__ h1, const float* __restrict__ s1,
    const int*   __restrict__ h2, const float* __restrict__ s2,
    float* __restrict__ part)
{
    __shared__ __align__(16) unsigned short smA_hi[128 * 32];
    __shared__ __align__(16) unsigned short smA_lo[128 * 32];
    __shared__ __align__(16) unsigned short smB_hi[128 * 32];
    __shared__ __align__(16) unsigned short smB_lo[128 * 32];
    __shared__ float bins[DDIM];                       // 32 KB private histogram
    __shared__ float4 metaA[128];                      // 2 KB scatter meta

    const int tid  = threadIdx.x;
    const int lane = tid & 63;
    const int wv   = tid >> 6;
    const int b    = blockIdx.x & 7;       // batch in low bits -> one batch/XCD
    const int pidx = blockIdx.x >> 3;      // triangular pair index

    // Triangular decode: pidx in [0,136) -> (tM, tN), tM <= tN, row-major
    int tM = 0, tN = 0;
    {
        int i = pidx;
#pragma unroll 1
        for (int t = 0; t < NTILE; ++t) {
            int cnt = NTILE - t;
            if (i < cnt) { tM = t; tN = t + i; break; }
            i -= cnt;
        }
    }
    const bool diag = (tM == tN);

    for (int i = tid; i < DDIM; i += 256) bins[i] = 0.0f;
    // (first __syncthreads inside k-loop orders this before any scatter)

    const int wrow = (wv >> 1) * 64;    // wave's 64x64 subtile origin
    const int wcol = (wv & 1) * 64;

    const size_t rowbaseA = ((size_t)b * CH + (size_t)tM * 128) * KPAD;
    const size_t rowbaseB = ((size_t)b * CH + (size_t)tN * 128) * KPAD;

    const unsigned short* fragBhi = diag ? smA_hi : smB_hi;
    const unsigned short* fragBlo = diag ? smA_lo : smB_lo;

    f32x4 acc[4][4];
    const f32x4 zv = {0.0f, 0.0f, 0.0f, 0.0f};
#pragma unroll
    for (int mi = 0; mi < 4; ++mi)
#pragma unroll
        for (int ni = 0; ni < 4; ++ni) acc[mi][ni] = zv;

    // fragment LDS offset: (row)*32 + fxor; XOR term is a per-lane constant
    const int fxor = (((lane >> 4) ^ ((lane >> 1) & 3)) << 3);
    const int rsel = lane & 15;

    for (int ks = 0; ks < KSTEPS; ++ks) {
        const int k0 = ks * 32;
        stage_tile(xhi, rowbaseA, smA_hi, wv, lane, k0);
        stage_tile(xlo, rowbaseA, smA_lo, wv, lane, k0);
        if (!diag) {
            stage_tile(xhi, rowbaseB, smB_hi, wv, lane, k0);
            stage_tile(xlo, rowbaseB, smB_lo, wv, lane, k0);
        }
        __syncthreads();

        bf16x8 ah[4], al[4], bh[4], bl[4];
#pragma unroll
        for (int i = 0; i < 4; ++i) {
            int offa = (wrow + i * 16 + rsel) * 32 + fxor;
            ah[i] = *(const bf16x8*)&smA_hi[offa];
            al[i] = *(const bf16x8*)&smA_lo[offa];
            int offb = (wcol + i * 16 + rsel) * 32 + fxor;
            bh[i] = *(const bf16x8*)&fragBhi[offb];
            bl[i] = *(const bf16x8*)&fragBlo[offb];
        }
#pragma unroll
        for (int mi = 0; mi < 4; ++mi)
#pragma unroll
            for (int ni = 0; ni < 4; ++ni) {
                acc[mi][ni] = __builtin_amdgcn_mfma_f32_16x16x32_bf16(ah[mi], bh[ni], acc[mi][ni], 0, 0, 0);
                acc[mi][ni] = __builtin_amdgcn_mfma_f32_16x16x32_bf16(ah[mi], bl[ni], acc[mi][ni], 0, 0, 0);
                acc[mi][ni] = __builtin_amdgcn_mfma_f32_16x16x32_bf16(al[mi], bh[ni], acc[mi][ni], 0, 0, 0);
            }
        __syncthreads();
    }

    // Stage scatter meta for this tile's 128 c1-rows into LDS.
    if (tid < 128) {
        int c1 = tM * 128 + tid;
        metaA[tid] = make_float4(s1[c1], __int_as_float(h1[c1]),
                                 s2[c1], __int_as_float(h2[c1]));
    }
    __syncthreads();

    // Scatter the 128x128 Gram tile into the LDS histogram.
    // C/D layout (m89-verified): col = lane&15, row = (lane>>4)*4 + reg
    // Off-diagonal pair: each entry contributes twice (G symmetric).
    const int c2b = tN * 128 + wcol + (lane & 15);
    const int rowsel = wrow + ((lane >> 4) << 2);
    int   h1c[4], h2c[4]; float s1c[4], s2c[4];
#pragma unroll
    for (int ni = 0; ni < 4; ++ni) {
        int c2 = c2b + ni * 16;
        h1c[ni] = h1[c2]; s1c[ni] = s1[c2];
        h2c[ni] = h2[c2]; s2c[ni] = s2[c2];
    }
#pragma unroll
    for (int mi = 0; mi < 4; ++mi) {
#pragma unroll
        for (int r = 0; r < 4; ++r) {
            float4 m = metaA[rowsel + mi * 16 + r];    // one ds_read_b128
            const float s1r = m.x, s2r = m.z;
            const int h1r = __float_as_int(m.y);
            const int h2r = __float_as_int(m.w);
#pragma unroll
            for (int ni = 0; ni < 4; ++ni) {
                float g = acc[mi][ni][r];
                atomicAdd(&bins[(h1r + h2c[ni]) & (DDIM - 1)], s1r * s2c[ni] * g);
                if (!diag)
                    atomicAdd(&bins[(h1c[ni] + h2r) & (DDIM - 1)], s1c[ni] * s2r * g);
            }
        }
    }

    __syncthreads();   // all scatters into bins complete

    // Flush to one of 17 part slots (8 blocks/slot), rotated start per block
    // to decontend cache lines.
    float* pb = part + ((size_t)((pidx % NSLOT) * BATCH + b) * DDIM);
    const int rot = (blockIdx.x & 31) << 8;
    for (int i = tid; i < DDIM; i += 256) {
        int j = (i + rot) & (DDIM - 1);
        atomicAdd(&pb[j], bins[j]);
    }
}

// ---------------------------------------------------------------------------
// Kernel 3: y[b,d] = sum over 17 part slots; accumulate norm[b] += sum|y|.
// grid 64: block j -> batch j>>3, d-slice (j&7)*1024.
// ---------------------------------------------------------------------------
__global__ __launch_bounds__(256) void reduce_kernel(
    const float* __restrict__ part, float* __restrict__ y,
    float* __restrict__ norm)
{
    const int tid = threadIdx.x;
    const int b  = blockIdx.x >> 3;
    const int d0 = (blockIdx.x & 7) * 1024;
    float ab = 0.0f;
    for (int dd = tid; dd < 1024; dd += 256) {
        int d = d0 + dd;
        float s = 0.0f;
#pragma unroll
        for (int p = 0; p < NSLOT; ++p)
            s += part[((size_t)p * BATCH + b) * DDIM + d];
        y[(size_t)b * DDIM + d] = s;
        ab += fabsf(s);   // sum|y| == sum feat_unnorm^2
    }
    __shared__ float red[256];
    red[tid] = ab;
    __syncthreads();
    for (int s = 128; s > 0; s >>= 1) {
        if (tid < s) red[tid] += red[tid + s];
        __syncthreads();
    }
    if (tid == 0) atomicAdd(&norm[b], red[0]);
}

// ---------------------------------------------------------------------------
// Kernel 4: fused signed-sqrt + L2-normalize + classifier GEMV.
// grid 64: block j owns d in [128j, 128j+128) for all batches.
// Writes feat to out and atomically accumulates bias-seeded logits.
// ---------------------------------------------------------------------------
__global__ __launch_bounds__(256) void logit_kernel(
    const float* __restrict__ y, const float* __restrict__ norm,
    const float* __restrict__ W, float* __restrict__ out)
{
    const int j = blockIdx.x;
    const int tid = threadIdx.x;
    __shared__ float fs[BATCH][128];                   // 4 KB
    for (int i = tid; i < BATCH * 128; i += 256) {
        int bb = i >> 7, dd = i & 127;
        float v = y[(size_t)bb * DDIM + j * 128 + dd];
        float inv = 1.0f / fmaxf(sqrtf(norm[bb]), 1e-12f);
        float f = copysignf(sqrtf(fabsf(v)), v) * inv;
        fs[bb][dd] = f;
        out[BATCH * NCLS + (size_t)bb * DDIM + j * 128 + dd] = f;
    }
    __syncthreads();
    if (tid < NCLS) {
        float a[BATCH];
#pragma unroll
        for (int bb = 0; bb < BATCH; ++bb) a[bb] = 0.0f;
        for (int dd = 0; dd < 128; ++dd) {
            float w = W[(size_t)(j * 128 + dd) * NCLS + tid];
#pragma unroll
            for (int bb = 0; bb < BATCH; ++bb) a[bb] += fs[bb][dd] * w;
        }
#pragma unroll
        for (int bb = 0; bb < BATCH; ++bb)
            atomicAdd(&out[bb * NCLS + tid], a[bb]);
    }
}

// ---------------------------------------------------------------------------
extern "C" void kernel_launch(void* const* d_in, const int* in_sizes, int n_in,
                              void* d_out, int out_size, void* d_ws, size_t ws_size,
                              hipStream_t stream)
{
    const float* x  = (const float*)d_in[0];
    const float* s1 = (const float*)d_in[1];
    const float* s2 = (const float*)d_in[2];
    const float* W  = (const float*)d_in[3];
    const float* bc = (const float*)d_in[4];
    const int*   h1 = (const int*)d_in[5];
    const int*   h2 = (const int*)d_in[6];
    float* out = (float*)d_out;

    // workspace layout: part (4.46MB) | y (256KB) | norm (256B) | xhi | xlo
    char* ws = (char*)d_ws;
    float* part = (float*)ws;
    const size_t partbytes = (size_t)NSLOT * BATCH * DDIM * sizeof(float);
    float* y    = (float*)(ws + partbytes);
    const size_t ybytes = (size_t)BATCH * DDIM * sizeof(float);
    float* norm = (float*)(ws + partbytes + ybytes);
    unsigned short* xhi = (unsigned short*)(ws + partbytes + ybytes + 256);
    unsigned short* xlo = xhi + (size_t)BATCH * CH * KPAD;

    split_kernel<<<(BATCH * CH * KPAD / 4 + 255) / 256, 256, 0, stream>>>(
        x, xhi, xlo, part, norm, bc, out);

    gram_scatter_kernel<<<NPAIR * BATCH, 256, 0, stream>>>(
        xhi, xlo, h1, s1, h2, s2, part);

    reduce_kernel<<<64, 256, 0, stream>>>(part, y, norm);

    logit_kernel<<<64, 256, 0, stream>>>(y, norm, W, out);
}